// Round 2
// baseline (3873.796 us; speedup 1.0000x reference)
//
#include <hip/hip_runtime.h>
#include <hip/hip_bf16.h>
#include <math.h>

using bf16 = __hip_bfloat16;

static __device__ __forceinline__ float b2f(bf16 v) { return __bfloat162float(v); }
static __device__ __forceinline__ bf16  f2b(float v) { return __float2bfloat16(v); }

// Problem constants
constexpr int B_   = 8;
constexpr int CIN_ = 3;
constexpr int H_   = 256;
constexpr int W_   = 256;
constexpr int ED_  = 64;
constexpr int WS_  = 8;
constexpr int SHIFT_ = 4;
constexpr int NWH_ = 32;      // H_/WS_
constexpr float EPS_ = 1e-5f;
constexpr float SCALE_ = 0.25f; // HD^-0.5, HD=16

// ---------------------------------------------------------------------------
// Kernel 1: conv embed 3x3, CIN=3 -> ED=64, NCHW f32 in -> NHWC bf16 out
// ---------------------------------------------------------------------------
__global__ __launch_bounds__(256) void k_conv_embed(
    const float* __restrict__ x, const float* __restrict__ we,
    const float* __restrict__ be, bf16* __restrict__ xe)
{
    int idx = blockIdx.x * 256 + threadIdx.x;        // ((b*H + h)*W + w)*64 + oc
    int oc  = idx & 63;
    int pix = idx >> 6;
    int w = pix & 255, h = (pix >> 8) & 255, b = pix >> 16;
    const float* xb = x + (size_t)b * (CIN_ * H_ * W_);
    float acc = be[oc];
#pragma unroll
    for (int ci = 0; ci < 3; ++ci) {
#pragma unroll
        for (int kh = 0; kh < 3; ++kh) {
            int hy = h + kh - 1;
            if ((unsigned)hy >= 256u) continue;
#pragma unroll
            for (int kw = 0; kw < 3; ++kw) {
                int wx = w + kw - 1;
                if ((unsigned)wx >= 256u) continue;
                acc += xb[(ci * 256 + hy) * 256 + wx] *
                       we[(oc * 3 + ci) * 9 + kh * 3 + kw];
            }
        }
    }
    xe[idx] = f2b(acc);
}

// ---------------------------------------------------------------------------
// Kernel 2: shifted-window attention. One block (256 thr) per window.
// Roll fused into addressing; mask computed analytically.
// ---------------------------------------------------------------------------
__global__ __launch_bounds__(256) void k_attn(
    const bf16* __restrict__ xe, const float* __restrict__ qkv_w,
    const float* __restrict__ qkv_b, const float* __restrict__ proj_w,
    const float* __restrict__ proj_b, const float* __restrict__ n1_g,
    const float* __restrict__ n1_b, bf16* __restrict__ x_out)
{
    __shared__ bf16 s_tok[64][66];    // [channel][token], padded stride 66
    __shared__ bf16 s_qkv[192][64];   // [o][token]  (q:0-63 scaled, k:64-127, v:128-191)
    __shared__ bf16 s_w[192 * 64];    // qkv weights, later proj weights

    const int t   = threadIdx.x;
    const int bi  = blockIdx.x;
    const int b   = bi >> 10;
    const int win = bi & 1023;
    const int wh  = win >> 5;
    const int wwi = win & 31;

    const bf16* xeb = xe + (size_t)b * (H_ * W_ * ED_);

    // ---- stage 1: load window tokens (rolled) + qkv weights ----
    for (int i = 0; i < 16; ++i) {
        int e = i * 256 + t;
        int n = e >> 6, c = e & 63;
        int hp = (wh * WS_ + (n >> 3) + SHIFT_) & 255;
        int wp = (wwi * WS_ + (n & 7) + SHIFT_) & 255;
        s_tok[c][n] = xeb[(hp * W_ + wp) * ED_ + c];
    }
    for (int i = 0; i < 48; ++i) {
        int e = i * 256 + t;
        s_w[e] = f2b(qkv_w[e]);
    }
    __syncthreads();

    // ---- stage 2: LayerNorm (thread per token) ----
    if (t < 64) {
        float s = 0.f, sq = 0.f;
#pragma unroll 16
        for (int c = 0; c < 64; ++c) { float v = b2f(s_tok[c][t]); s += v; sq += v * v; }
        float m   = s * (1.f / 64.f);
        float var = sq * (1.f / 64.f) - m * m;
        float rstd = rsqrtf(var + EPS_);
#pragma unroll 16
        for (int c = 0; c < 64; ++c) {
            float v = (b2f(s_tok[c][t]) - m) * rstd;
            s_tok[c][t] = f2b(v * n1_g[c] + n1_b[c]);
        }
    }
    __syncthreads();

    // ---- stage 3: QKV projection (each thread: 48 outputs of one token) ----
    {
        const int n = t & 63, g = t >> 6;
        for (int oo = 0; oo < 48; ++oo) {
            int o = g * 48 + oo;
            float acc = qkv_b[o];
#pragma unroll 16
            for (int c = 0; c < 64; ++c)
                acc += b2f(s_tok[c][n]) * b2f(s_w[o * 64 + c]);
            if (o < 64) acc *= SCALE_;
            s_qkv[o][n] = f2b(acc);
        }
    }
    __syncthreads();

    // ---- stage 4: load proj weights (reuse s_w) + attention ----
    for (int i = 0; i < 16; ++i) {
        int e = i * 256 + t;
        s_w[e] = f2b(proj_w[e]);
    }
    {
        const int h = t >> 6, n = t & 63;   // wave = head, lane = query token
        float qv[16];
#pragma unroll
        for (int d = 0; d < 16; ++d) qv[d] = b2f(s_qkv[h * 16 + d][n]);

        int rr = n >> 3, cc = n & 7;
        int cn = ((wh == NWH_ - 1) ? (1 + (rr >= SHIFT_)) : 0) * 3 +
                 ((wwi == NWH_ - 1) ? (1 + (cc >= SHIFT_)) : 0);

        float sc[64];
        float mx = -1e30f;
#pragma unroll
        for (int m = 0; m < 64; ++m) {
            float s = 0.f;
#pragma unroll
            for (int d = 0; d < 16; ++d)
                s += qv[d] * b2f(s_qkv[64 + h * 16 + d][m]);
            int r2 = m >> 3, c2 = m & 7;
            int cm = ((wh == NWH_ - 1) ? (1 + (r2 >= SHIFT_)) : 0) * 3 +
                     ((wwi == NWH_ - 1) ? (1 + (c2 >= SHIFT_)) : 0);
            s += (cm != cn) ? -100.f : 0.f;
            sc[m] = s;
            mx = fmaxf(mx, s);
        }
        float ssum = 0.f;
#pragma unroll
        for (int m = 0; m < 64; ++m) { float e = __expf(sc[m] - mx); sc[m] = e; ssum += e; }
        float inv = 1.f / ssum;
#pragma unroll
        for (int d = 0; d < 16; ++d) {
            float a = 0.f;
#pragma unroll
            for (int m = 0; m < 64; ++m)
                a += sc[m] * b2f(s_qkv[128 + h * 16 + d][m]);
            s_tok[h * 16 + d][n] = f2b(a * inv);   // attn out, overwrites xn (dead)
        }
    }
    __syncthreads();

    // ---- stage 5: proj + residual + store (window-reverse + roll fused) ----
    {
        const int n = t & 63, g = t >> 6;
        int hp = (wh * WS_ + (n >> 3) + SHIFT_) & 255;
        int wp = (wwi * WS_ + (n & 7) + SHIFT_) & 255;
        size_t base = (size_t)b * (H_ * W_ * ED_) + (size_t)(hp * W_ + wp) * ED_;
#pragma unroll
        for (int i = 0; i < 16; ++i) {
            int o = g * 16 + i;
            float acc = proj_b[o];
#pragma unroll 16
            for (int c = 0; c < 64; ++c)
                acc += b2f(s_tok[c][n]) * b2f(s_w[o * 64 + c]);
            acc += b2f(xeb[(hp * W_ + wp) * ED_ + o]);   // residual (pre-LN token)
            x_out[base + o] = f2b(acc);
        }
    }
}

// ---------------------------------------------------------------------------
// Kernel 3: LN2 + fc1(64->256) + exact GELU + fc2(256->64) + residual
// ---------------------------------------------------------------------------
__global__ __launch_bounds__(256) void k_mlp(
    const bf16* __restrict__ xo, const float* __restrict__ fc1_w,
    const float* __restrict__ fc1_b, const float* __restrict__ fc2_w,
    const float* __restrict__ fc2_b, const float* __restrict__ n2_g,
    const float* __restrict__ n2_b, bf16* __restrict__ xf)
{
    __shared__ bf16 s_x[64][66];    // normalized tokens [c][n]
    __shared__ bf16 s_h[64][66];    // hidden chunk [hc][n]
    __shared__ bf16 s_w1[4096];     // fc1 chunk [o2][c]
    __shared__ bf16 s_w2[4096];     // fc2 chunk [o][cl]

    const int t = threadIdx.x;
    const size_t tok0 = (size_t)blockIdx.x * 64;

    for (int i = 0; i < 16; ++i) {
        int e = i * 256 + t;
        int n = e >> 6, c = e & 63;
        s_x[c][n] = xo[(tok0 + n) * 64 + c];
    }
    __syncthreads();

    if (t < 64) {
        float s = 0.f, sq = 0.f;
#pragma unroll 16
        for (int c = 0; c < 64; ++c) { float v = b2f(s_x[c][t]); s += v; sq += v * v; }
        float m   = s * (1.f / 64.f);
        float var = sq * (1.f / 64.f) - m * m;
        float rstd = rsqrtf(var + EPS_);
#pragma unroll 16
        for (int c = 0; c < 64; ++c) {
            float v = (b2f(s_x[c][t]) - m) * rstd;
            s_x[c][t] = f2b(v * n2_g[c] + n2_b[c]);
        }
    }
    __syncthreads();

    const int n = t & 63, g = t >> 6;
    float acc[16];
#pragma unroll
    for (int i = 0; i < 16; ++i) acc[i] = 0.f;

    for (int k = 0; k < 4; ++k) {
        for (int i = 0; i < 16; ++i) {
            int e = i * 256 + t;
            s_w1[e] = f2b(fc1_w[k * 4096 + e]);            // rows k*64..k*64+63
            int o = e >> 6, cl = e & 63;
            s_w2[e] = f2b(fc2_w[o * 256 + k * 64 + cl]);   // cols k*64..k*64+63
        }
        __syncthreads();

        // fc1 chunk + GELU
        for (int i = 0; i < 16; ++i) {
            int o2 = g * 16 + i;
            float a = fc1_b[k * 64 + o2];
#pragma unroll 16
            for (int c = 0; c < 64; ++c)
                a += b2f(s_x[c][n]) * b2f(s_w1[o2 * 64 + c]);
            a = 0.5f * a * (1.f + erff(a * 0.70710678118f));
            s_h[o2][n] = f2b(a);
        }
        __syncthreads();

        // fc2 partial accumulate
#pragma unroll
        for (int i = 0; i < 16; ++i) {
            int o = g * 16 + i;
            float a = acc[i];
#pragma unroll 16
            for (int cl = 0; cl < 64; ++cl)
                a += b2f(s_h[cl][n]) * b2f(s_w2[o * 64 + cl]);
            acc[i] = a;
        }
        __syncthreads();
    }

#pragma unroll
    for (int i = 0; i < 16; ++i) {
        int o = g * 16 + i;
        float v = acc[i] + fc2_b[o] + b2f(xo[(tok0 + n) * 64 + o]);
        xf[(tok0 + n) * 64 + o] = f2b(v);
    }
}

// ---------------------------------------------------------------------------
// Kernel 4: conv up 3x3, ED=64 -> CIN=3 (NHWC bf16 in, NCHW f32 out) + residual.
// One wave per pixel, lane = input channel -> coalesced reads.
// ---------------------------------------------------------------------------
__global__ __launch_bounds__(256) void k_conv_up(
    const float* __restrict__ x, const bf16* __restrict__ xf,
    const float* __restrict__ wu, const float* __restrict__ bu,
    float* __restrict__ out)
{
    __shared__ float s_w[9 * 3 * 64];   // [tap][co][ci]
    const int t = threadIdx.x;
    for (int i = 0; i < 7; ++i) {
        int e = i * 256 + t;
        if (e < 1728) {
            int tap = e / 192, rem = e % 192, co = rem >> 6, ci = rem & 63;
            s_w[e] = wu[(co * 64 + ci) * 9 + tap];   // wu[co][ci][kh][kw]
        }
    }
    __syncthreads();

    const int lane = t & 63;
    const int wv   = t >> 6;
    int pix = blockIdx.x * 4 + wv;
    int b = pix >> 16, h = (pix >> 8) & 255, w = pix & 255;

    float a0 = 0.f, a1 = 0.f, a2 = 0.f;
#pragma unroll
    for (int kh = 0; kh < 3; ++kh) {
        int hy = h + kh - 1;
        if ((unsigned)hy >= 256u) continue;
#pragma unroll
        for (int kw = 0; kw < 3; ++kw) {
            int wx = w + kw - 1;
            if ((unsigned)wx >= 256u) continue;
            float xv = b2f(xf[((size_t)(b * 256 + hy) * 256 + wx) * 64 + lane]);
            int tap = kh * 3 + kw;
            a0 += xv * s_w[tap * 192 + lane];
            a1 += xv * s_w[tap * 192 + 64 + lane];
            a2 += xv * s_w[tap * 192 + 128 + lane];
        }
    }
#pragma unroll
    for (int off = 32; off; off >>= 1) {
        a0 += __shfl_xor(a0, off);
        a1 += __shfl_xor(a1, off);
        a2 += __shfl_xor(a2, off);
    }
    if (lane == 0) {
        size_t o0 = (size_t)b * 3 * 65536 + (size_t)h * 256 + w;
        out[o0]           = a0 + bu[0] + x[o0];
        out[o0 + 65536]   = a1 + bu[1] + x[o0 + 65536];
        out[o0 + 131072]  = a2 + bu[2] + x[o0 + 131072];
    }
}

// ---------------------------------------------------------------------------
extern "C" void kernel_launch(void* const* d_in, const int* in_sizes, int n_in,
                              void* d_out, int out_size, void* d_ws, size_t ws_size,
                              hipStream_t stream)
{
    const float* x     = (const float*)d_in[0];
    const float* cew   = (const float*)d_in[1];
    const float* ceb   = (const float*)d_in[2];
    const float* n1g   = (const float*)d_in[3];
    const float* n1b   = (const float*)d_in[4];
    const float* qkvw  = (const float*)d_in[5];
    const float* qkvb  = (const float*)d_in[6];
    const float* projw = (const float*)d_in[7];
    const float* projb = (const float*)d_in[8];
    const float* n2g   = (const float*)d_in[9];
    const float* n2b   = (const float*)d_in[10];
    const float* fc1w  = (const float*)d_in[11];
    const float* fc1b  = (const float*)d_in[12];
    const float* fc2w  = (const float*)d_in[13];
    const float* fc2b  = (const float*)d_in[14];
    const float* cuw   = (const float*)d_in[15];
    const float* cub   = (const float*)d_in[16];
    float* out = (float*)d_out;

    const size_t planeElems = (size_t)B_ * H_ * W_ * ED_;   // 33.5M
    bf16* xe = (bf16*)d_ws;                                  // also x_final later
    bf16* xo = (bf16*)((char*)d_ws + planeElems * sizeof(bf16));

    hipLaunchKernelGGL(k_conv_embed, dim3(131072), dim3(256), 0, stream, x, cew, ceb, xe);
    hipLaunchKernelGGL(k_attn,       dim3(8192),   dim3(256), 0, stream,
                       xe, qkvw, qkvb, projw, projb, n1g, n1b, xo);
    hipLaunchKernelGGL(k_mlp,        dim3(8192),   dim3(256), 0, stream,
                       xo, fc1w, fc1b, fc2w, fc2b, n2g, n2b, xe);
    hipLaunchKernelGGL(k_conv_up,    dim3(131072), dim3(256), 0, stream, x, xe, cuw, cub, out);
}

// Round 3
// 1643.626 us; speedup vs baseline: 2.3569x; 2.3569x over previous
//
#include <hip/hip_runtime.h>
#include <hip/hip_bf16.h>
#include <math.h>

using bf16 = __hip_bfloat16;

typedef short s16x8 __attribute__((ext_vector_type(8)));
typedef short s16x4 __attribute__((ext_vector_type(4)));
typedef float f32x4 __attribute__((ext_vector_type(4)));

static __device__ __forceinline__ float s2f(short s) {
    return __uint_as_float(((unsigned)(unsigned short)s) << 16);
}
static __device__ __forceinline__ short f2s(float v) {
    bf16 b = __float2bfloat16(v);
    return *reinterpret_cast<short*>(&b);
}
static __device__ __forceinline__ float b2f(bf16 v) { return __bfloat162float(v); }
static __device__ __forceinline__ bf16  f2b(float v) { return __float2bfloat16(v); }

// 64-col bf16 LDS tile, XOR-swizzled 16B blocks: elem index for (row, col)
static __device__ __forceinline__ int lswz(int row, int col) {
    return row * 64 + ((((col >> 3) ^ row) & 7) << 3) + (col & 7);
}
// col must be a multiple of 8 (start of a 16B block)
static __device__ __forceinline__ int lbase(int row, int col) {
    return row * 64 + ((((col >> 3) ^ row) & 7) << 3);
}
static __device__ __forceinline__ s16x8 ld8(const short* p) {
    return *(const s16x8*)p;
}
static __device__ __forceinline__ f32x4 mfma16(s16x8 a, s16x8 b, f32x4 c) {
    return __builtin_amdgcn_mfma_f32_16x16x32_bf16(a, b, c, 0, 0, 0);
}

constexpr int B_   = 8;
constexpr int CIN_ = 3;
constexpr int H_   = 256;
constexpr int W_   = 256;
constexpr int ED_  = 64;
constexpr float EPS_ = 1e-5f;

// region class for shifted-window mask (SHIFT=4, WS=8)
static __device__ __forceinline__ int clsf(int tok, int eh, int ew) {
    int ch = eh ? (1 + ((tok >> 3) >= 4)) : 0;
    int cw = ew ? (1 + ((tok & 7) >= 4)) : 0;
    return ch * 3 + cw;
}

// ---------------------------------------------------------------------------
// Kernel 1: conv embed 3x3, CIN=3 -> ED=64, NCHW f32 in -> NHWC bf16 out
// ---------------------------------------------------------------------------
__global__ __launch_bounds__(256) void k_conv_embed(
    const float* __restrict__ x, const float* __restrict__ we,
    const float* __restrict__ be, bf16* __restrict__ xe)
{
    int idx = blockIdx.x * 256 + threadIdx.x;
    int oc  = idx & 63;
    int pix = idx >> 6;
    int w = pix & 255, h = (pix >> 8) & 255, b = pix >> 16;
    const float* xb = x + (size_t)b * (CIN_ * H_ * W_);
    float acc = be[oc];
#pragma unroll
    for (int ci = 0; ci < 3; ++ci) {
#pragma unroll
        for (int kh = 0; kh < 3; ++kh) {
            int hy = h + kh - 1;
            if ((unsigned)hy >= 256u) continue;
#pragma unroll
            for (int kw = 0; kw < 3; ++kw) {
                int wx = w + kw - 1;
                if ((unsigned)wx >= 256u) continue;
                acc += xb[(ci * 256 + hy) * 256 + wx] *
                       we[(oc * 3 + ci) * 9 + kh * 3 + kw];
            }
        }
    }
    xe[idx] = f2b(acc);
}

// ---------------------------------------------------------------------------
// Kernel 2: shifted-window attention, MFMA. One block (256 thr) per window.
// wave = head. All GEMMs 16x16x32 bf16, swizzled LDS.
// ---------------------------------------------------------------------------
__global__ __launch_bounds__(256) void k_attn(
    const bf16* __restrict__ xe, const float* __restrict__ qkv_w,
    const float* __restrict__ qkv_b, const float* __restrict__ proj_w,
    const float* __restrict__ proj_b, const float* __restrict__ n1_g,
    const float* __restrict__ n1_b, bf16* __restrict__ x_out)
{
    __shared__ short s_x[64 * 64];     // Xn (post-LN); later P head 0
    __shared__ short s_w[192 * 64];    // qkv weights; later P heads 1..3
    __shared__ short s_q[64 * 64];     // Q (scaled); later attn-out O
    __shared__ short s_k[64 * 64];     // K
    __shared__ short s_vt[64 * 64];    // V^T [d][tok]
    __shared__ short s_wp[64 * 64];    // proj weights

    const int t    = threadIdx.x;
    const int w    = t >> 6;
    const int lane = t & 63;
    const int lr   = lane & 15;
    const int lhi  = lane >> 4;

    const int bi  = blockIdx.x;
    const int b   = bi >> 10;
    const int wh  = (bi >> 5) & 31;
    const int wwi = bi & 31;
    const int eh  = (wh == 31), ew = (wwi == 31);

    const bf16* xeb = xe + (size_t)b * (H_ * W_ * ED_);

    // ---- stage 1: weights -> LDS (fp32->bf16, swizzled) + token load + LN ----
#pragma unroll
    for (int i = 0; i < 12; ++i) {              // qkv_w: 12288 elems = 3072 quads
        int g = i * 256 + t;
        int row = g >> 4, c4 = (g & 15) << 2;
        float4 v = *(const float4*)&qkv_w[row * 64 + c4];
        s16x4 p = { f2s(v.x), f2s(v.y), f2s(v.z), f2s(v.w) };
        *(s16x4*)&s_w[lswz(row, c4)] = p;
    }
#pragma unroll
    for (int i = 0; i < 4; ++i) {               // proj_w: 4096 elems
        int g = i * 256 + t;
        int row = g >> 4, c4 = (g & 15) << 2;
        float4 v = *(const float4*)&proj_w[row * 64 + c4];
        s16x4 p = { f2s(v.x), f2s(v.y), f2s(v.z), f2s(v.w) };
        *(s16x4*)&s_wp[lswz(row, c4)] = p;
    }
    {
        // LN: 4 threads per token, 16 channels each
        int n = t >> 2, q = t & 3;
        int hp = (wh * 8 + (n >> 3) + 4) & 255;
        int wp = (wwi * 8 + (n & 7) + 4) & 255;
        const short* src = (const short*)xeb + (hp * 256 + wp) * 64 + q * 16;
        s16x8 u0 = *(const s16x8*)src;
        s16x8 u1 = *(const s16x8*)(src + 8);
        float v[16];
        float s = 0.f, sq = 0.f;
#pragma unroll
        for (int j = 0; j < 8; ++j) { v[j] = s2f(u0[j]); v[8 + j] = s2f(u1[j]); }
#pragma unroll
        for (int j = 0; j < 16; ++j) { s += v[j]; sq += v[j] * v[j]; }
        s  += __shfl_xor(s, 1);  s  += __shfl_xor(s, 2);
        sq += __shfl_xor(sq, 1); sq += __shfl_xor(sq, 2);
        float m = s * (1.f / 64.f);
        float rstd = rsqrtf(sq * (1.f / 64.f) - m * m + EPS_);
        s16x8 w0, w1;
#pragma unroll
        for (int j = 0; j < 8; ++j) {
            w0[j] = f2s((v[j] - m) * rstd * n1_g[q * 16 + j] + n1_b[q * 16 + j]);
            w1[j] = f2s((v[8 + j] - m) * rstd * n1_g[q * 16 + 8 + j] + n1_b[q * 16 + 8 + j]);
        }
        *(s16x8*)&s_x[lbase(n, q * 16)]     = w0;
        *(s16x8*)&s_x[lbase(n, q * 16 + 8)] = w1;
    }
    __syncthreads();

    // ---- stage 2: QKV GEMMs ----
    {
        const f32x4 cz = { 0.f, 0.f, 0.f, 0.f };
        int arow = w * 16 + lr;
        s16x8 a0 = ld8(&s_x[lbase(arow, lhi * 8)]);
        s16x8 a1 = ld8(&s_x[lbase(arow, 32 + lhi * 8)]);
#pragma unroll
        for (int nt = 0; nt < 8; ++nt) {        // Q: nt 0..3, K: nt 4..7
            int brow = nt * 16 + lr;            // output index o
            s16x8 b0 = ld8(&s_w[lbase(brow, lhi * 8)]);
            s16x8 b1 = ld8(&s_w[lbase(brow, 32 + lhi * 8)]);
            f32x4 c = cz;
            c = mfma16(a0, b0, c);
            c = mfma16(a1, b1, c);
            float bias = qkv_b[brow];
#pragma unroll
            for (int r = 0; r < 4; ++r) {
                int tok = w * 16 + lhi * 4 + r;
                float val = c[r] + bias;
                if (nt < 4) { val *= 0.25f; s_q[lswz(tok, nt * 16 + lr)] = f2s(val); }
                else        {               s_k[lswz(tok, (nt - 4) * 16 + lr)] = f2s(val); }
            }
        }
        // V^T: A = Wv rows, B = Xn-transposed-access
        s16x8 av0 = ld8(&s_w[lbase(128 + w * 16 + lr, lhi * 8)]);
        s16x8 av1 = ld8(&s_w[lbase(128 + w * 16 + lr, 32 + lhi * 8)]);
#pragma unroll
        for (int nt = 0; nt < 4; ++nt) {
            s16x8 b0 = ld8(&s_x[lbase(nt * 16 + lr, lhi * 8)]);
            s16x8 b1 = ld8(&s_x[lbase(nt * 16 + lr, 32 + lhi * 8)]);
            f32x4 c = cz;
            c = mfma16(av0, b0, c);
            c = mfma16(av1, b1, c);
#pragma unroll
            for (int r = 0; r < 4; ++r) {
                int d = w * 16 + lhi * 4 + r;
                s_vt[lswz(d, nt * 16 + lr)] = f2s(c[r] + qkv_b[128 + d]);
            }
        }
    }
    __syncthreads();

    // ---- stage 3: S = Q K^T (K=16, zero-padded to 32) + mask + softmax ----
    short* p_lds = (w == 0) ? s_x : &s_w[(w - 1) * 4096];   // per-head P buffer
    {
        const int h = w;
        const f32x4 cz = { 0.f, 0.f, 0.f, 0.f };
        const s16x8 z8 = { 0, 0, 0, 0, 0, 0, 0, 0 };
        s16x8 qa[4], kb[4];
#pragma unroll
        for (int mt = 0; mt < 4; ++mt)
            qa[mt] = ld8(&s_q[lbase(mt * 16 + lr, h * 16 + (lhi & 1) * 8)]);
#pragma unroll
        for (int nt = 0; nt < 4; ++nt) {
            s16x8 v = ld8(&s_k[lbase(nt * 16 + lr, h * 16 + (lhi & 1) * 8)]);
            kb[nt] = (lhi >= 2) ? z8 : v;       // zero k>=16 contribution
        }
        f32x4 S[4][4];
#pragma unroll
        for (int mt = 0; mt < 4; ++mt)
#pragma unroll
            for (int nt = 0; nt < 4; ++nt)
                S[mt][nt] = mfma16(qa[mt], kb[nt], cz);

        if (eh | ew) {
            int kcls[4];
#pragma unroll
            for (int nt = 0; nt < 4; ++nt) kcls[nt] = clsf(nt * 16 + lr, eh, ew);
#pragma unroll
            for (int mt = 0; mt < 4; ++mt)
#pragma unroll
                for (int r = 0; r < 4; ++r) {
                    int qc = clsf(mt * 16 + lhi * 4 + r, eh, ew);
#pragma unroll
                    for (int nt = 0; nt < 4; ++nt)
                        S[mt][nt][r] += (qc != kcls[nt]) ? -100.f : 0.f;
                }
        }
        // wave-parallel softmax per row (row lives in one 16-lane group)
#pragma unroll
        for (int mt = 0; mt < 4; ++mt)
#pragma unroll
            for (int r = 0; r < 4; ++r) {
                float mx = fmaxf(fmaxf(S[mt][0][r], S[mt][1][r]),
                                 fmaxf(S[mt][2][r], S[mt][3][r]));
                mx = fmaxf(mx, __shfl_xor(mx, 1));
                mx = fmaxf(mx, __shfl_xor(mx, 2));
                mx = fmaxf(mx, __shfl_xor(mx, 4));
                mx = fmaxf(mx, __shfl_xor(mx, 8));
                float e0 = __expf(S[mt][0][r] - mx);
                float e1 = __expf(S[mt][1][r] - mx);
                float e2 = __expf(S[mt][2][r] - mx);
                float e3 = __expf(S[mt][3][r] - mx);
                float sm = e0 + e1 + e2 + e3;
                sm += __shfl_xor(sm, 1);
                sm += __shfl_xor(sm, 2);
                sm += __shfl_xor(sm, 4);
                sm += __shfl_xor(sm, 8);
                float inv = 1.f / sm;
                int qtok = mt * 16 + lhi * 4 + r;
                p_lds[lswz(qtok, 0 * 16 + lr)] = f2s(e0 * inv);
                p_lds[lswz(qtok, 1 * 16 + lr)] = f2s(e1 * inv);
                p_lds[lswz(qtok, 2 * 16 + lr)] = f2s(e2 * inv);
                p_lds[lswz(qtok, 3 * 16 + lr)] = f2s(e3 * inv);
            }
    }
    __syncthreads();

    // ---- stage 4: O = P V  (per head; write O to s_o = s_q overlay) ----
    short* s_o = s_q;
    {
        const int h = w;
        const f32x4 cz = { 0.f, 0.f, 0.f, 0.f };
        f32x4 O[4] = { cz, cz, cz, cz };
#pragma unroll
        for (int ks = 0; ks < 2; ++ks) {
            s16x8 bv = ld8(&s_vt[lbase(h * 16 + lr, ks * 32 + lhi * 8)]);
#pragma unroll
            for (int mt = 0; mt < 4; ++mt) {
                s16x8 pa = ld8(&p_lds[lbase(mt * 16 + lr, ks * 32 + lhi * 8)]);
                O[mt] = mfma16(pa, bv, O[mt]);
            }
        }
#pragma unroll
        for (int mt = 0; mt < 4; ++mt)
#pragma unroll
            for (int r = 0; r < 4; ++r) {
                int tok = mt * 16 + lhi * 4 + r;
                s_o[lswz(tok, h * 16 + lr)] = f2s(O[mt][r]);
            }
    }
    __syncthreads();

    // ---- stage 5: proj + residual + store (window-reverse + roll fused) ----
    {
        const f32x4 cz = { 0.f, 0.f, 0.f, 0.f };
        int arow = w * 16 + lr;
        s16x8 a0 = ld8(&s_o[lbase(arow, lhi * 8)]);
        s16x8 a1 = ld8(&s_o[lbase(arow, 32 + lhi * 8)]);
        size_t rowbase[4];
#pragma unroll
        for (int r = 0; r < 4; ++r) {
            int tok = w * 16 + lhi * 4 + r;
            int hp = (wh * 8 + (tok >> 3) + 4) & 255;
            int wp = (wwi * 8 + (tok & 7) + 4) & 255;
            rowbase[r] = (size_t)(hp * 256 + wp) * 64;
        }
        const size_t bbase = (size_t)b * (H_ * W_ * ED_);
#pragma unroll
        for (int nt = 0; nt < 4; ++nt) {
            s16x8 b0 = ld8(&s_wp[lbase(nt * 16 + lr, lhi * 8)]);
            s16x8 b1 = ld8(&s_wp[lbase(nt * 16 + lr, 32 + lhi * 8)]);
            f32x4 c = cz;
            c = mfma16(a0, b0, c);
            c = mfma16(a1, b1, c);
            float bias = proj_b[nt * 16 + lr];
#pragma unroll
            for (int r = 0; r < 4; ++r) {
                size_t gi = rowbase[r] + nt * 16 + lr;
                float val = c[r] + bias + b2f(xeb[gi]);
                x_out[bbase + gi] = f2b(val);
            }
        }
    }
}

// ---------------------------------------------------------------------------
// Kernel 3: LN2 + fc1 + GELU + fc2 + residual, MFMA. 128 tokens/block, 8 waves.
// ---------------------------------------------------------------------------
__global__ __launch_bounds__(512) void k_mlp(
    const bf16* __restrict__ xo, const float* __restrict__ fc1_w,
    const float* __restrict__ fc1_b, const float* __restrict__ fc2_w,
    const float* __restrict__ fc2_b, const float* __restrict__ n2_g,
    const float* __restrict__ n2_b, bf16* __restrict__ xf)
{
    __shared__ short s_x[128 * 64];    // normalized tokens
    __shared__ short s_h[128 * 64];    // hidden chunk (wave-private row stripes)
    __shared__ short s_w1[64 * 64];
    __shared__ short s_w2[64 * 64];

    const int t    = threadIdx.x;
    const int w    = t >> 6;
    const int lane = t & 63;
    const int lr   = lane & 15;
    const int lhi  = lane >> 4;
    const size_t tok0 = (size_t)blockIdx.x * 128;
    const short* xos = (const short*)xo;

    // LN: 4 threads per token
    {
        int n = t >> 2, q = t & 3;
        const short* src = xos + (tok0 + n) * 64 + q * 16;
        s16x8 u0 = *(const s16x8*)src;
        s16x8 u1 = *(const s16x8*)(src + 8);
        float v[16];
        float s = 0.f, sq = 0.f;
#pragma unroll
        for (int j = 0; j < 8; ++j) { v[j] = s2f(u0[j]); v[8 + j] = s2f(u1[j]); }
#pragma unroll
        for (int j = 0; j < 16; ++j) { s += v[j]; sq += v[j] * v[j]; }
        s  += __shfl_xor(s, 1);  s  += __shfl_xor(s, 2);
        sq += __shfl_xor(sq, 1); sq += __shfl_xor(sq, 2);
        float m = s * (1.f / 64.f);
        float rstd = rsqrtf(sq * (1.f / 64.f) - m * m + EPS_);
        s16x8 w0, w1;
#pragma unroll
        for (int j = 0; j < 8; ++j) {
            w0[j] = f2s((v[j] - m) * rstd * n2_g[q * 16 + j] + n2_b[q * 16 + j]);
            w1[j] = f2s((v[8 + j] - m) * rstd * n2_g[q * 16 + 8 + j] + n2_b[q * 16 + 8 + j]);
        }
        *(s16x8*)&s_x[lbase(n, q * 16)]     = w0;
        *(s16x8*)&s_x[lbase(n, q * 16 + 8)] = w1;
    }

    const f32x4 cz = { 0.f, 0.f, 0.f, 0.f };
    f32x4 acc[4] = { cz, cz, cz, cz };
    const int arow = w * 16 + lr;

    for (int k = 0; k < 4; ++k) {
        __syncthreads();
        // stage fc1/fc2 weight chunks (fp32 -> bf16, swizzled)
#pragma unroll
        for (int i = 0; i < 2; ++i) {
            int g = i * 512 + t;
            int row = g >> 4, c4 = (g & 15) << 2;
            float4 a = *(const float4*)&fc1_w[(k * 64 + row) * 64 + c4];
            s16x4 pa = { f2s(a.x), f2s(a.y), f2s(a.z), f2s(a.w) };
            *(s16x4*)&s_w1[lswz(row, c4)] = pa;
            float4 bb = *(const float4*)&fc2_w[row * 256 + k * 64 + c4];
            s16x4 pb = { f2s(bb.x), f2s(bb.y), f2s(bb.z), f2s(bb.w) };
            *(s16x4*)&s_w2[lswz(row, c4)] = pb;
        }
        __syncthreads();

        // fc1 chunk + GELU -> s_h (own 16-row stripe)
        s16x8 a0 = ld8(&s_x[lbase(arow, lhi * 8)]);
        s16x8 a1 = ld8(&s_x[lbase(arow, 32 + lhi * 8)]);
#pragma unroll
        for (int nt = 0; nt < 4; ++nt) {
            s16x8 b0 = ld8(&s_w1[lbase(nt * 16 + lr, lhi * 8)]);
            s16x8 b1 = ld8(&s_w1[lbase(nt * 16 + lr, 32 + lhi * 8)]);
            f32x4 c = cz;
            c = mfma16(a0, b0, c);
            c = mfma16(a1, b1, c);
            float bias = fc1_b[k * 64 + nt * 16 + lr];
#pragma unroll
            for (int r = 0; r < 4; ++r) {
                float hv = c[r] + bias;
                hv = 0.5f * hv * (1.f + erff(hv * 0.70710678118f));
                s_h[lswz(w * 16 + lhi * 4 + r, nt * 16 + lr)] = f2s(hv);
            }
        }
        // fc2 partial (reads own stripe; same-wave LDS ordering)
        s16x8 h0 = ld8(&s_h[lbase(arow, lhi * 8)]);
        s16x8 h1 = ld8(&s_h[lbase(arow, 32 + lhi * 8)]);
#pragma unroll
        for (int nt = 0; nt < 4; ++nt) {
            s16x8 b0 = ld8(&s_w2[lbase(nt * 16 + lr, lhi * 8)]);
            s16x8 b1 = ld8(&s_w2[lbase(nt * 16 + lr, 32 + lhi * 8)]);
            acc[nt] = mfma16(h0, b0, acc[nt]);
            acc[nt] = mfma16(h1, b1, acc[nt]);
        }
    }

    // epilogue: bias + residual + store
#pragma unroll
    for (int nt = 0; nt < 4; ++nt) {
        float bias = fc2_b[nt * 16 + lr];
#pragma unroll
        for (int r = 0; r < 4; ++r) {
            int tok = w * 16 + lhi * 4 + r;
            size_t gi = (tok0 + tok) * 64 + nt * 16 + lr;
            float v = acc[nt][r] + bias + s2f(xos[gi]);
            ((short*)xf)[gi] = f2s(v);
        }
    }
}

// ---------------------------------------------------------------------------
// Kernel 4: conv up 3x3, ED=64 -> CIN=3 (NHWC bf16 in, NCHW f32 out) + residual
// ---------------------------------------------------------------------------
__global__ __launch_bounds__(256) void k_conv_up(
    const float* __restrict__ x, const bf16* __restrict__ xf,
    const float* __restrict__ wu, const float* __restrict__ bu,
    float* __restrict__ out)
{
    __shared__ float s_w[9 * 3 * 64];   // [tap][co][ci]
    const int t = threadIdx.x;
    for (int i = 0; i < 7; ++i) {
        int e = i * 256 + t;
        if (e < 1728) {
            int tap = e / 192, rem = e % 192, co = rem >> 6, ci = rem & 63;
            s_w[e] = wu[(co * 64 + ci) * 9 + tap];
        }
    }
    __syncthreads();

    const int lane = t & 63;
    const int wv   = t >> 6;
    int pix = blockIdx.x * 4 + wv;
    int b = pix >> 16, h = (pix >> 8) & 255, w = pix & 255;

    float a0 = 0.f, a1 = 0.f, a2 = 0.f;
#pragma unroll
    for (int kh = 0; kh < 3; ++kh) {
        int hy = h + kh - 1;
        if ((unsigned)hy >= 256u) continue;
#pragma unroll
        for (int kw = 0; kw < 3; ++kw) {
            int wx = w + kw - 1;
            if ((unsigned)wx >= 256u) continue;
            float xv = b2f(xf[((size_t)(b * 256 + hy) * 256 + wx) * 64 + lane]);
            int tap = kh * 3 + kw;
            a0 += xv * s_w[tap * 192 + lane];
            a1 += xv * s_w[tap * 192 + 64 + lane];
            a2 += xv * s_w[tap * 192 + 128 + lane];
        }
    }
#pragma unroll
    for (int off = 32; off; off >>= 1) {
        a0 += __shfl_xor(a0, off);
        a1 += __shfl_xor(a1, off);
        a2 += __shfl_xor(a2, off);
    }
    if (lane == 0) {
        size_t o0 = (size_t)b * 3 * 65536 + (size_t)h * 256 + w;
        out[o0]          = a0 + bu[0] + x[o0];
        out[o0 + 65536]  = a1 + bu[1] + x[o0 + 65536];
        out[o0 + 131072] = a2 + bu[2] + x[o0 + 131072];
    }
}

// ---------------------------------------------------------------------------
extern "C" void kernel_launch(void* const* d_in, const int* in_sizes, int n_in,
                              void* d_out, int out_size, void* d_ws, size_t ws_size,
                              hipStream_t stream)
{
    const float* x     = (const float*)d_in[0];
    const float* cew   = (const float*)d_in[1];
    const float* ceb   = (const float*)d_in[2];
    const float* n1g   = (const float*)d_in[3];
    const float* n1b   = (const float*)d_in[4];
    const float* qkvw  = (const float*)d_in[5];
    const float* qkvb  = (const float*)d_in[6];
    const float* projw = (const float*)d_in[7];
    const float* projb = (const float*)d_in[8];
    const float* n2g   = (const float*)d_in[9];
    const float* n2b   = (const float*)d_in[10];
    const float* fc1w  = (const float*)d_in[11];
    const float* fc1b  = (const float*)d_in[12];
    const float* fc2w  = (const float*)d_in[13];
    const float* fc2b  = (const float*)d_in[14];
    const float* cuw   = (const float*)d_in[15];
    const float* cub   = (const float*)d_in[16];
    float* out = (float*)d_out;

    const size_t planeElems = (size_t)B_ * H_ * W_ * ED_;   // 33.5M
    bf16* xe = (bf16*)d_ws;                                  // also x_final later
    bf16* xo = (bf16*)((char*)d_ws + planeElems * sizeof(bf16));

    hipLaunchKernelGGL(k_conv_embed, dim3(131072), dim3(256), 0, stream, x, cew, ceb, xe);
    hipLaunchKernelGGL(k_attn,       dim3(8192),   dim3(256), 0, stream,
                       xe, qkvw, qkvb, projw, projb, n1g, n1b, xo);
    hipLaunchKernelGGL(k_mlp,        dim3(4096),   dim3(512), 0, stream,
                       xo, fc1w, fc1b, fc2w, fc2b, n2g, n2b, xe);
    hipLaunchKernelGGL(k_conv_up,    dim3(131072), dim3(256), 0, stream, x, xe, cuw, cub, out);
}

// Round 4
// 779.427 us; speedup vs baseline: 4.9701x; 2.1088x over previous
//
#include <hip/hip_runtime.h>
#include <hip/hip_bf16.h>
#include <math.h>

using bf16 = __hip_bfloat16;

typedef short s16x8 __attribute__((ext_vector_type(8)));
typedef short s16x4 __attribute__((ext_vector_type(4)));
typedef float f32x4 __attribute__((ext_vector_type(4)));

static __device__ __forceinline__ float s2f(short s) {
    return __uint_as_float(((unsigned)(unsigned short)s) << 16);
}
static __device__ __forceinline__ short f2s(float v) {
    bf16 b = __float2bfloat16(v);
    return *reinterpret_cast<short*>(&b);
}
static __device__ __forceinline__ float b2f(bf16 v) { return __bfloat162float(v); }
static __device__ __forceinline__ bf16  f2b(float v) { return __float2bfloat16(v); }

// 64-col bf16 LDS tile, XOR-swizzled 16B blocks: elem index for (row, col)
static __device__ __forceinline__ int lswz(int row, int col) {
    return row * 64 + ((((col >> 3) ^ row) & 7) << 3) + (col & 7);
}
// col must be a multiple of 8 (start of a 16B block)
static __device__ __forceinline__ int lbase(int row, int col) {
    return row * 64 + ((((col >> 3) ^ row) & 7) << 3);
}
static __device__ __forceinline__ s16x8 ld8(const short* p) {
    return *(const s16x8*)p;
}
static __device__ __forceinline__ f32x4 mfma16(s16x8 a, s16x8 b, f32x4 c) {
    return __builtin_amdgcn_mfma_f32_16x16x32_bf16(a, b, c, 0, 0, 0);
}

constexpr int B_   = 8;
constexpr int CIN_ = 3;
constexpr int H_   = 256;
constexpr int W_   = 256;
constexpr int ED_  = 64;
constexpr float EPS_ = 1e-5f;

// region class for shifted-window mask (SHIFT=4, WS=8)
static __device__ __forceinline__ int clsf(int tok, int eh, int ew) {
    int ch = eh ? (1 + ((tok >> 3) >= 4)) : 0;
    int cw = ew ? (1 + ((tok & 7) >= 4)) : 0;
    return ch * 3 + cw;
}

// ---------------------------------------------------------------------------
// Kernel 1: conv embed 3x3, CIN=3 -> ED=64, NCHW f32 in -> NHWC bf16 out.
// wave = 64-pixel row segment, lane = pixel. 27 x-values in registers;
// weights read at wave-uniform addresses (s_load broadcast). No LDS needed.
// ---------------------------------------------------------------------------
__global__ __launch_bounds__(256) void k_conv_embed(
    const float* __restrict__ x, const float* __restrict__ we,
    const float* __restrict__ be, bf16* __restrict__ xe)
{
    const int t    = threadIdx.x;
    const int wv   = t >> 6;
    const int lane = t & 63;
    const int hb   = blockIdx.x;          // b*256 + h
    const int h    = hb & 255;
    const int b    = hb >> 8;
    const int col  = wv * 64 + lane;

    const float* xb = x + (size_t)b * (CIN_ * H_ * W_);

    // 27 receptive-field values in registers (coalesced loads, zero-pad OOB)
    float xr[27];
#pragma unroll
    for (int ci = 0; ci < 3; ++ci)
#pragma unroll
        for (int kh = 0; kh < 3; ++kh) {
            int hy = h + kh - 1;
#pragma unroll
            for (int kw = 0; kw < 3; ++kw) {
                int wx = col + kw - 1;
                bool ok = ((unsigned)hy < 256u) & ((unsigned)wx < 256u);
                xr[ci * 9 + kh * 3 + kw] = ok ? xb[ci * 65536 + hy * 256 + wx] : 0.f;
            }
        }

    // 64 output channels, processed in pairs -> packed bf16 dwords
    unsigned pk[32];
#pragma unroll 4
    for (int op = 0; op < 32; ++op) {
        float a0 = be[2 * op];
        float a1 = be[2 * op + 1];
        const float* w0 = we + (2 * op) * 27;   // (oc,ci,kh,kw) = oc*27 + ci*9 + kh*3 + kw
#pragma unroll
        for (int k = 0; k < 27; ++k) {
            a0 += xr[k] * w0[k];
            a1 += xr[k] * w0[27 + k];
        }
        pk[op] = (unsigned)(unsigned short)f2s(a0) |
                 ((unsigned)(unsigned short)f2s(a1) << 16);
    }

    // store 128B contiguous per lane (8 x dwordx4)
    size_t pixel = (size_t)hb * 256 + col;
    uint4* dst = (uint4*)((short*)xe + pixel * 64);
#pragma unroll
    for (int i = 0; i < 8; ++i) dst[i] = *(uint4*)&pk[i * 4];
}

// ---------------------------------------------------------------------------
// Kernel 2: shifted-window attention, MFMA. One block (256 thr) per window.
// wave = head. All GEMMs 16x16x32 bf16, swizzled LDS.
// ---------------------------------------------------------------------------
__global__ __launch_bounds__(256) void k_attn(
    const bf16* __restrict__ xe, const float* __restrict__ qkv_w,
    const float* __restrict__ qkv_b, const float* __restrict__ proj_w,
    const float* __restrict__ proj_b, const float* __restrict__ n1_g,
    const float* __restrict__ n1_b, bf16* __restrict__ x_out)
{
    __shared__ short s_x[64 * 64];     // Xn (post-LN); later P head 0
    __shared__ short s_w[192 * 64];    // qkv weights; later P heads 1..3
    __shared__ short s_q[64 * 64];     // Q (scaled); later attn-out O
    __shared__ short s_k[64 * 64];     // K
    __shared__ short s_vt[64 * 64];    // V^T [d][tok]
    __shared__ short s_wp[64 * 64];    // proj weights

    const int t    = threadIdx.x;
    const int w    = t >> 6;
    const int lane = t & 63;
    const int lr   = lane & 15;
    const int lhi  = lane >> 4;

    const int bi  = blockIdx.x;
    const int b   = bi >> 10;
    const int wh  = (bi >> 5) & 31;
    const int wwi = bi & 31;
    const int eh  = (wh == 31), ew = (wwi == 31);

    const bf16* xeb = xe + (size_t)b * (H_ * W_ * ED_);

    // ---- stage 1: weights -> LDS (fp32->bf16, swizzled) + token load + LN ----
#pragma unroll
    for (int i = 0; i < 12; ++i) {              // qkv_w: 12288 elems = 3072 quads
        int g = i * 256 + t;
        int row = g >> 4, c4 = (g & 15) << 2;
        float4 v = *(const float4*)&qkv_w[row * 64 + c4];
        s16x4 p = { f2s(v.x), f2s(v.y), f2s(v.z), f2s(v.w) };
        *(s16x4*)&s_w[lswz(row, c4)] = p;
    }
#pragma unroll
    for (int i = 0; i < 4; ++i) {               // proj_w: 4096 elems
        int g = i * 256 + t;
        int row = g >> 4, c4 = (g & 15) << 2;
        float4 v = *(const float4*)&proj_w[row * 64 + c4];
        s16x4 p = { f2s(v.x), f2s(v.y), f2s(v.z), f2s(v.w) };
        *(s16x4*)&s_wp[lswz(row, c4)] = p;
    }
    {
        // LN: 4 threads per token, 16 channels each
        int n = t >> 2, q = t & 3;
        int hp = (wh * 8 + (n >> 3) + 4) & 255;
        int wp = (wwi * 8 + (n & 7) + 4) & 255;
        const short* src = (const short*)xeb + (hp * 256 + wp) * 64 + q * 16;
        s16x8 u0 = *(const s16x8*)src;
        s16x8 u1 = *(const s16x8*)(src + 8);
        float v[16];
        float s = 0.f, sq = 0.f;
#pragma unroll
        for (int j = 0; j < 8; ++j) { v[j] = s2f(u0[j]); v[8 + j] = s2f(u1[j]); }
#pragma unroll
        for (int j = 0; j < 16; ++j) { s += v[j]; sq += v[j] * v[j]; }
        s  += __shfl_xor(s, 1);  s  += __shfl_xor(s, 2);
        sq += __shfl_xor(sq, 1); sq += __shfl_xor(sq, 2);
        float m = s * (1.f / 64.f);
        float rstd = rsqrtf(sq * (1.f / 64.f) - m * m + EPS_);
        s16x8 w0, w1;
#pragma unroll
        for (int j = 0; j < 8; ++j) {
            w0[j] = f2s((v[j] - m) * rstd * n1_g[q * 16 + j] + n1_b[q * 16 + j]);
            w1[j] = f2s((v[8 + j] - m) * rstd * n1_g[q * 16 + 8 + j] + n1_b[q * 16 + 8 + j]);
        }
        *(s16x8*)&s_x[lbase(n, q * 16)]     = w0;
        *(s16x8*)&s_x[lbase(n, q * 16 + 8)] = w1;
    }
    __syncthreads();

    // ---- stage 2: QKV GEMMs ----
    {
        const f32x4 cz = { 0.f, 0.f, 0.f, 0.f };
        int arow = w * 16 + lr;
        s16x8 a0 = ld8(&s_x[lbase(arow, lhi * 8)]);
        s16x8 a1 = ld8(&s_x[lbase(arow, 32 + lhi * 8)]);
#pragma unroll
        for (int nt = 0; nt < 8; ++nt) {        // Q: nt 0..3, K: nt 4..7
            int brow = nt * 16 + lr;            // output index o
            s16x8 b0 = ld8(&s_w[lbase(brow, lhi * 8)]);
            s16x8 b1 = ld8(&s_w[lbase(brow, 32 + lhi * 8)]);
            f32x4 c = cz;
            c = mfma16(a0, b0, c);
            c = mfma16(a1, b1, c);
            float bias = qkv_b[brow];
#pragma unroll
            for (int r = 0; r < 4; ++r) {
                int tok = w * 16 + lhi * 4 + r;
                float val = c[r] + bias;
                if (nt < 4) { val *= 0.25f; s_q[lswz(tok, nt * 16 + lr)] = f2s(val); }
                else        {               s_k[lswz(tok, (nt - 4) * 16 + lr)] = f2s(val); }
            }
        }
        // V^T: A = Wv rows, B = Xn-transposed-access
        s16x8 av0 = ld8(&s_w[lbase(128 + w * 16 + lr, lhi * 8)]);
        s16x8 av1 = ld8(&s_w[lbase(128 + w * 16 + lr, 32 + lhi * 8)]);
#pragma unroll
        for (int nt = 0; nt < 4; ++nt) {
            s16x8 b0 = ld8(&s_x[lbase(nt * 16 + lr, lhi * 8)]);
            s16x8 b1 = ld8(&s_x[lbase(nt * 16 + lr, 32 + lhi * 8)]);
            f32x4 c = cz;
            c = mfma16(av0, b0, c);
            c = mfma16(av1, b1, c);
#pragma unroll
            for (int r = 0; r < 4; ++r) {
                int d = w * 16 + lhi * 4 + r;
                s_vt[lswz(d, nt * 16 + lr)] = f2s(c[r] + qkv_b[128 + d]);
            }
        }
    }
    __syncthreads();

    // ---- stage 3: S = Q K^T (K=16, zero-padded to 32) + mask + softmax ----
    short* p_lds = (w == 0) ? s_x : &s_w[(w - 1) * 4096];   // per-head P buffer
    {
        const int h = w;
        const f32x4 cz = { 0.f, 0.f, 0.f, 0.f };
        const s16x8 z8 = { 0, 0, 0, 0, 0, 0, 0, 0 };
        s16x8 qa[4], kb[4];
#pragma unroll
        for (int mt = 0; mt < 4; ++mt)
            qa[mt] = ld8(&s_q[lbase(mt * 16 + lr, h * 16 + (lhi & 1) * 8)]);
#pragma unroll
        for (int nt = 0; nt < 4; ++nt) {
            s16x8 v = ld8(&s_k[lbase(nt * 16 + lr, h * 16 + (lhi & 1) * 8)]);
            kb[nt] = (lhi >= 2) ? z8 : v;       // zero k>=16 contribution
        }
        f32x4 S[4][4];
#pragma unroll
        for (int mt = 0; mt < 4; ++mt)
#pragma unroll
            for (int nt = 0; nt < 4; ++nt)
                S[mt][nt] = mfma16(qa[mt], kb[nt], cz);

        if (eh | ew) {
            int kcls[4];
#pragma unroll
            for (int nt = 0; nt < 4; ++nt) kcls[nt] = clsf(nt * 16 + lr, eh, ew);
#pragma unroll
            for (int mt = 0; mt < 4; ++mt)
#pragma unroll
                for (int r = 0; r < 4; ++r) {
                    int qc = clsf(mt * 16 + lhi * 4 + r, eh, ew);
#pragma unroll
                    for (int nt = 0; nt < 4; ++nt)
                        S[mt][nt][r] += (qc != kcls[nt]) ? -100.f : 0.f;
                }
        }
        // wave-parallel softmax per row (row lives in one 16-lane group)
#pragma unroll
        for (int mt = 0; mt < 4; ++mt)
#pragma unroll
            for (int r = 0; r < 4; ++r) {
                float mx = fmaxf(fmaxf(S[mt][0][r], S[mt][1][r]),
                                 fmaxf(S[mt][2][r], S[mt][3][r]));
                mx = fmaxf(mx, __shfl_xor(mx, 1));
                mx = fmaxf(mx, __shfl_xor(mx, 2));
                mx = fmaxf(mx, __shfl_xor(mx, 4));
                mx = fmaxf(mx, __shfl_xor(mx, 8));
                float e0 = __expf(S[mt][0][r] - mx);
                float e1 = __expf(S[mt][1][r] - mx);
                float e2 = __expf(S[mt][2][r] - mx);
                float e3 = __expf(S[mt][3][r] - mx);
                float sm = e0 + e1 + e2 + e3;
                sm += __shfl_xor(sm, 1);
                sm += __shfl_xor(sm, 2);
                sm += __shfl_xor(sm, 4);
                sm += __shfl_xor(sm, 8);
                float inv = 1.f / sm;
                int qtok = mt * 16 + lhi * 4 + r;
                p_lds[lswz(qtok, 0 * 16 + lr)] = f2s(e0 * inv);
                p_lds[lswz(qtok, 1 * 16 + lr)] = f2s(e1 * inv);
                p_lds[lswz(qtok, 2 * 16 + lr)] = f2s(e2 * inv);
                p_lds[lswz(qtok, 3 * 16 + lr)] = f2s(e3 * inv);
            }
    }
    __syncthreads();

    // ---- stage 4: O = P V  (per head; write O to s_o = s_q overlay) ----
    short* s_o = s_q;
    {
        const int h = w;
        const f32x4 cz = { 0.f, 0.f, 0.f, 0.f };
        f32x4 O[4] = { cz, cz, cz, cz };
#pragma unroll
        for (int ks = 0; ks < 2; ++ks) {
            s16x8 bv = ld8(&s_vt[lbase(h * 16 + lr, ks * 32 + lhi * 8)]);
#pragma unroll
            for (int mt = 0; mt < 4; ++mt) {
                s16x8 pa = ld8(&p_lds[lbase(mt * 16 + lr, ks * 32 + lhi * 8)]);
                O[mt] = mfma16(pa, bv, O[mt]);
            }
        }
#pragma unroll
        for (int mt = 0; mt < 4; ++mt)
#pragma unroll
            for (int r = 0; r < 4; ++r) {
                int tok = mt * 16 + lhi * 4 + r;
                s_o[lswz(tok, h * 16 + lr)] = f2s(O[mt][r]);
            }
    }
    __syncthreads();

    // ---- stage 5: proj + residual + store (window-reverse + roll fused) ----
    {
        const f32x4 cz = { 0.f, 0.f, 0.f, 0.f };
        int arow = w * 16 + lr;
        s16x8 a0 = ld8(&s_o[lbase(arow, lhi * 8)]);
        s16x8 a1 = ld8(&s_o[lbase(arow, 32 + lhi * 8)]);
        size_t rowbase[4];
#pragma unroll
        for (int r = 0; r < 4; ++r) {
            int tok = w * 16 + lhi * 4 + r;
            int hp = (wh * 8 + (tok >> 3) + 4) & 255;
            int wp = (wwi * 8 + (tok & 7) + 4) & 255;
            rowbase[r] = (size_t)(hp * 256 + wp) * 64;
        }
        const size_t bbase = (size_t)b * (H_ * W_ * ED_);
#pragma unroll
        for (int nt = 0; nt < 4; ++nt) {
            s16x8 b0 = ld8(&s_wp[lbase(nt * 16 + lr, lhi * 8)]);
            s16x8 b1 = ld8(&s_wp[lbase(nt * 16 + lr, 32 + lhi * 8)]);
            f32x4 c = cz;
            c = mfma16(a0, b0, c);
            c = mfma16(a1, b1, c);
            float bias = proj_b[nt * 16 + lr];
#pragma unroll
            for (int r = 0; r < 4; ++r) {
                size_t gi = rowbase[r] + nt * 16 + lr;
                float val = c[r] + bias + b2f(xeb[gi]);
                x_out[bbase + gi] = f2b(val);
            }
        }
    }
}

// ---------------------------------------------------------------------------
// Kernel 3: LN2 + fc1 + GELU + fc2 + residual, MFMA. 128 tokens/block, 8 waves.
// ---------------------------------------------------------------------------
__global__ __launch_bounds__(512) void k_mlp(
    const bf16* __restrict__ xo, const float* __restrict__ fc1_w,
    const float* __restrict__ fc1_b, const float* __restrict__ fc2_w,
    const float* __restrict__ fc2_b, const float* __restrict__ n2_g,
    const float* __restrict__ n2_b, bf16* __restrict__ xf)
{
    __shared__ short s_x[128 * 64];    // normalized tokens
    __shared__ short s_h[128 * 64];    // hidden chunk (wave-private row stripes)
    __shared__ short s_w1[64 * 64];
    __shared__ short s_w2[64 * 64];

    const int t    = threadIdx.x;
    const int w    = t >> 6;
    const int lane = t & 63;
    const int lr   = lane & 15;
    const int lhi  = lane >> 4;
    const size_t tok0 = (size_t)blockIdx.x * 128;
    const short* xos = (const short*)xo;

    // LN: 4 threads per token
    {
        int n = t >> 2, q = t & 3;
        const short* src = xos + (tok0 + n) * 64 + q * 16;
        s16x8 u0 = *(const s16x8*)src;
        s16x8 u1 = *(const s16x8*)(src + 8);
        float v[16];
        float s = 0.f, sq = 0.f;
#pragma unroll
        for (int j = 0; j < 8; ++j) { v[j] = s2f(u0[j]); v[8 + j] = s2f(u1[j]); }
#pragma unroll
        for (int j = 0; j < 16; ++j) { s += v[j]; sq += v[j] * v[j]; }
        s  += __shfl_xor(s, 1);  s  += __shfl_xor(s, 2);
        sq += __shfl_xor(sq, 1); sq += __shfl_xor(sq, 2);
        float m = s * (1.f / 64.f);
        float rstd = rsqrtf(sq * (1.f / 64.f) - m * m + EPS_);
        s16x8 w0, w1;
#pragma unroll
        for (int j = 0; j < 8; ++j) {
            w0[j] = f2s((v[j] - m) * rstd * n2_g[q * 16 + j] + n2_b[q * 16 + j]);
            w1[j] = f2s((v[8 + j] - m) * rstd * n2_g[q * 16 + 8 + j] + n2_b[q * 16 + 8 + j]);
        }
        *(s16x8*)&s_x[lbase(n, q * 16)]     = w0;
        *(s16x8*)&s_x[lbase(n, q * 16 + 8)] = w1;
    }

    const f32x4 cz = { 0.f, 0.f, 0.f, 0.f };
    f32x4 acc[4] = { cz, cz, cz, cz };
    const int arow = w * 16 + lr;

    for (int k = 0; k < 4; ++k) {
        __syncthreads();
        // stage fc1/fc2 weight chunks (fp32 -> bf16, swizzled)
#pragma unroll
        for (int i = 0; i < 2; ++i) {
            int g = i * 512 + t;
            int row = g >> 4, c4 = (g & 15) << 2;
            float4 a = *(const float4*)&fc1_w[(k * 64 + row) * 64 + c4];
            s16x4 pa = { f2s(a.x), f2s(a.y), f2s(a.z), f2s(a.w) };
            *(s16x4*)&s_w1[lswz(row, c4)] = pa;
            float4 bb = *(const float4*)&fc2_w[row * 256 + k * 64 + c4];
            s16x4 pb = { f2s(bb.x), f2s(bb.y), f2s(bb.z), f2s(bb.w) };
            *(s16x4*)&s_w2[lswz(row, c4)] = pb;
        }
        __syncthreads();

        // fc1 chunk + GELU -> s_h (own 16-row stripe)
        s16x8 a0 = ld8(&s_x[lbase(arow, lhi * 8)]);
        s16x8 a1 = ld8(&s_x[lbase(arow, 32 + lhi * 8)]);
#pragma unroll
        for (int nt = 0; nt < 4; ++nt) {
            s16x8 b0 = ld8(&s_w1[lbase(nt * 16 + lr, lhi * 8)]);
            s16x8 b1 = ld8(&s_w1[lbase(nt * 16 + lr, 32 + lhi * 8)]);
            f32x4 c = cz;
            c = mfma16(a0, b0, c);
            c = mfma16(a1, b1, c);
            float bias = fc1_b[k * 64 + nt * 16 + lr];
#pragma unroll
            for (int r = 0; r < 4; ++r) {
                float hv = c[r] + bias;
                hv = 0.5f * hv * (1.f + erff(hv * 0.70710678118f));
                s_h[lswz(w * 16 + lhi * 4 + r, nt * 16 + lr)] = f2s(hv);
            }
        }
        // fc2 partial (reads own stripe; same-wave LDS ordering)
        s16x8 h0 = ld8(&s_h[lbase(arow, lhi * 8)]);
        s16x8 h1 = ld8(&s_h[lbase(arow, 32 + lhi * 8)]);
#pragma unroll
        for (int nt = 0; nt < 4; ++nt) {
            s16x8 b0 = ld8(&s_w2[lbase(nt * 16 + lr, lhi * 8)]);
            s16x8 b1 = ld8(&s_w2[lbase(nt * 16 + lr, 32 + lhi * 8)]);
            acc[nt] = mfma16(h0, b0, acc[nt]);
            acc[nt] = mfma16(h1, b1, acc[nt]);
        }
    }

    // epilogue: bias + residual + store
#pragma unroll
    for (int nt = 0; nt < 4; ++nt) {
        float bias = fc2_b[nt * 16 + lr];
#pragma unroll
        for (int r = 0; r < 4; ++r) {
            int tok = w * 16 + lhi * 4 + r;
            size_t gi = (tok0 + tok) * 64 + nt * 16 + lr;
            float v = acc[nt][r] + bias + s2f(xos[gi]);
            ((short*)xf)[gi] = f2s(v);
        }
    }
}

// ---------------------------------------------------------------------------
// Kernel 4: conv up 3x3, ED=64 -> CIN=3 (NHWC bf16 in, NCHW f32 out) + residual
// ---------------------------------------------------------------------------
__global__ __launch_bounds__(256) void k_conv_up(
    const float* __restrict__ x, const bf16* __restrict__ xf,
    const float* __restrict__ wu, const float* __restrict__ bu,
    float* __restrict__ out)
{
    __shared__ float s_w[9 * 3 * 64];   // [tap][co][ci]
    const int t = threadIdx.x;
    for (int i = 0; i < 7; ++i) {
        int e = i * 256 + t;
        if (e < 1728) {
            int tap = e / 192, rem = e % 192, co = rem >> 6, ci = rem & 63;
            s_w[e] = wu[(co * 64 + ci) * 9 + tap];
        }
    }
    __syncthreads();

    const int lane = t & 63;
    const int wv   = t >> 6;
    int pix = blockIdx.x * 4 + wv;
    int b = pix >> 16, h = (pix >> 8) & 255, w = pix & 255;

    float a0 = 0.f, a1 = 0.f, a2 = 0.f;
#pragma unroll
    for (int kh = 0; kh < 3; ++kh) {
        int hy = h + kh - 1;
        if ((unsigned)hy >= 256u) continue;
#pragma unroll
        for (int kw = 0; kw < 3; ++kw) {
            int wx = w + kw - 1;
            if ((unsigned)wx >= 256u) continue;
            float xv = b2f(xf[((size_t)(b * 256 + hy) * 256 + wx) * 64 + lane]);
            int tap = kh * 3 + kw;
            a0 += xv * s_w[tap * 192 + lane];
            a1 += xv * s_w[tap * 192 + 64 + lane];
            a2 += xv * s_w[tap * 192 + 128 + lane];
        }
    }
#pragma unroll
    for (int off = 32; off; off >>= 1) {
        a0 += __shfl_xor(a0, off);
        a1 += __shfl_xor(a1, off);
        a2 += __shfl_xor(a2, off);
    }
    if (lane == 0) {
        size_t o0 = (size_t)b * 3 * 65536 + (size_t)h * 256 + w;
        out[o0]          = a0 + bu[0] + x[o0];
        out[o0 + 65536]  = a1 + bu[1] + x[o0 + 65536];
        out[o0 + 131072] = a2 + bu[2] + x[o0 + 131072];
    }
}

// ---------------------------------------------------------------------------
extern "C" void kernel_launch(void* const* d_in, const int* in_sizes, int n_in,
                              void* d_out, int out_size, void* d_ws, size_t ws_size,
                              hipStream_t stream)
{
    const float* x     = (const float*)d_in[0];
    const float* cew   = (const float*)d_in[1];
    const float* ceb   = (const float*)d_in[2];
    const float* n1g   = (const float*)d_in[3];
    const float* n1b   = (const float*)d_in[4];
    const float* qkvw  = (const float*)d_in[5];
    const float* qkvb  = (const float*)d_in[6];
    const float* projw = (const float*)d_in[7];
    const float* projb = (const float*)d_in[8];
    const float* n2g   = (const float*)d_in[9];
    const float* n2b   = (const float*)d_in[10];
    const float* fc1w  = (const float*)d_in[11];
    const float* fc1b  = (const float*)d_in[12];
    const float* fc2w  = (const float*)d_in[13];
    const float* fc2b  = (const float*)d_in[14];
    const float* cuw   = (const float*)d_in[15];
    const float* cub   = (const float*)d_in[16];
    float* out = (float*)d_out;

    const size_t planeElems = (size_t)B_ * H_ * W_ * ED_;   // 33.5M
    bf16* xe = (bf16*)d_ws;                                  // also x_final later
    bf16* xo = (bf16*)((char*)d_ws + planeElems * sizeof(bf16));

    hipLaunchKernelGGL(k_conv_embed, dim3(2048),   dim3(256), 0, stream, x, cew, ceb, xe);
    hipLaunchKernelGGL(k_attn,       dim3(8192),   dim3(256), 0, stream,
                       xe, qkvw, qkvb, projw, projb, n1g, n1b, xo);
    hipLaunchKernelGGL(k_mlp,        dim3(4096),   dim3(512), 0, stream,
                       xo, fc1w, fc1b, fc2w, fc2b, n2g, n2b, xe);
    hipLaunchKernelGGL(k_conv_up,    dim3(131072), dim3(256), 0, stream, x, xe, cuw, cub, out);
}

// Round 5
// 506.686 us; speedup vs baseline: 7.6454x; 1.5383x over previous
//
#include <hip/hip_runtime.h>
#include <hip/hip_bf16.h>
#include <math.h>

using bf16 = __hip_bfloat16;

typedef short s16x8 __attribute__((ext_vector_type(8)));
typedef short s16x4 __attribute__((ext_vector_type(4)));
typedef float f32x4 __attribute__((ext_vector_type(4)));

static __device__ __forceinline__ float s2f(short s) {
    return __uint_as_float(((unsigned)(unsigned short)s) << 16);
}
static __device__ __forceinline__ short f2s(float v) {
    bf16 b = __float2bfloat16(v);
    return *reinterpret_cast<short*>(&b);
}
static __device__ __forceinline__ float b2f(bf16 v) { return __bfloat162float(v); }
static __device__ __forceinline__ bf16  f2b(float v) { return __float2bfloat16(v); }

// 64-col bf16 LDS tile, XOR-swizzled 16B blocks: elem index for (row, col)
static __device__ __forceinline__ int lswz(int row, int col) {
    return row * 64 + ((((col >> 3) ^ row) & 7) << 3) + (col & 7);
}
// col must be a multiple of 8 (start of a 16B block)
static __device__ __forceinline__ int lbase(int row, int col) {
    return row * 64 + ((((col >> 3) ^ row) & 7) << 3);
}
static __device__ __forceinline__ s16x8 ld8(const short* p) {
    return *(const s16x8*)p;
}
static __device__ __forceinline__ f32x4 mfma16(s16x8 a, s16x8 b, f32x4 c) {
    return __builtin_amdgcn_mfma_f32_16x16x32_bf16(a, b, c, 0, 0, 0);
}

constexpr int B_   = 8;
constexpr int CIN_ = 3;
constexpr int H_   = 256;
constexpr int W_   = 256;
constexpr int ED_  = 64;
constexpr float EPS_ = 1e-5f;

// region class for shifted-window mask (SHIFT=4, WS=8)
static __device__ __forceinline__ int clsf(int tok, int eh, int ew) {
    int ch = eh ? (1 + ((tok >> 3) >= 4)) : 0;
    int cw = ew ? (1 + ((tok & 7) >= 4)) : 0;
    return ch * 3 + cw;
}

// ---------------------------------------------------------------------------
// Kernel 1: conv embed 3x3, CIN=3 -> ED=64, NCHW f32 in -> NHWC bf16 out.
// wave = 64-pixel row segment, lane = pixel. 27 x-values in registers;
// weights read at wave-uniform addresses (s_load broadcast). No LDS needed.
// ---------------------------------------------------------------------------
__global__ __launch_bounds__(256) void k_conv_embed(
    const float* __restrict__ x, const float* __restrict__ we,
    const float* __restrict__ be, bf16* __restrict__ xe)
{
    const int t    = threadIdx.x;
    const int wv   = t >> 6;
    const int lane = t & 63;
    const int hb   = blockIdx.x;          // b*256 + h
    const int h    = hb & 255;
    const int b    = hb >> 8;
    const int col  = wv * 64 + lane;

    const float* xb = x + (size_t)b * (CIN_ * H_ * W_);

    // 27 receptive-field values in registers (coalesced loads, zero-pad OOB)
    float xr[27];
#pragma unroll
    for (int ci = 0; ci < 3; ++ci)
#pragma unroll
        for (int kh = 0; kh < 3; ++kh) {
            int hy = h + kh - 1;
#pragma unroll
            for (int kw = 0; kw < 3; ++kw) {
                int wx = col + kw - 1;
                bool ok = ((unsigned)hy < 256u) & ((unsigned)wx < 256u);
                xr[ci * 9 + kh * 3 + kw] = ok ? xb[ci * 65536 + hy * 256 + wx] : 0.f;
            }
        }

    // 64 output channels, processed in pairs -> packed bf16 dwords
    unsigned pk[32];
#pragma unroll 4
    for (int op = 0; op < 32; ++op) {
        float a0 = be[2 * op];
        float a1 = be[2 * op + 1];
        const float* w0 = we + (2 * op) * 27;   // (oc,ci,kh,kw) = oc*27 + ci*9 + kh*3 + kw
#pragma unroll
        for (int k = 0; k < 27; ++k) {
            a0 += xr[k] * w0[k];
            a1 += xr[k] * w0[27 + k];
        }
        pk[op] = (unsigned)(unsigned short)f2s(a0) |
                 ((unsigned)(unsigned short)f2s(a1) << 16);
    }

    // store 128B contiguous per lane (8 x dwordx4)
    size_t pixel = (size_t)hb * 256 + col;
    uint4* dst = (uint4*)((short*)xe + pixel * 64);
#pragma unroll
    for (int i = 0; i < 8; ++i) dst[i] = *(uint4*)&pk[i * 4];
}

// ---------------------------------------------------------------------------
// Kernel 2: shifted-window attention, MFMA. One block (256 thr) per window.
// wave = head. All GEMMs 16x16x32 bf16, swizzled LDS.
// ---------------------------------------------------------------------------
__global__ __launch_bounds__(256) void k_attn(
    const bf16* __restrict__ xe, const float* __restrict__ qkv_w,
    const float* __restrict__ qkv_b, const float* __restrict__ proj_w,
    const float* __restrict__ proj_b, const float* __restrict__ n1_g,
    const float* __restrict__ n1_b, bf16* __restrict__ x_out)
{
    __shared__ short s_x[64 * 64];     // Xn (post-LN); later P head 0
    __shared__ short s_w[192 * 64];    // qkv weights; later P heads 1..3
    __shared__ short s_q[64 * 64];     // Q (scaled); later attn-out O
    __shared__ short s_k[64 * 64];     // K
    __shared__ short s_vt[64 * 64];    // V^T [d][tok]
    __shared__ short s_wp[64 * 64];    // proj weights

    const int t    = threadIdx.x;
    const int w    = t >> 6;
    const int lane = t & 63;
    const int lr   = lane & 15;
    const int lhi  = lane >> 4;

    const int bi  = blockIdx.x;
    const int b   = bi >> 10;
    const int wh  = (bi >> 5) & 31;
    const int wwi = bi & 31;
    const int eh  = (wh == 31), ew = (wwi == 31);

    const bf16* xeb = xe + (size_t)b * (H_ * W_ * ED_);

    // ---- stage 1: weights -> LDS (fp32->bf16, swizzled) + token load + LN ----
#pragma unroll
    for (int i = 0; i < 12; ++i) {              // qkv_w: 12288 elems = 3072 quads
        int g = i * 256 + t;
        int row = g >> 4, c4 = (g & 15) << 2;
        float4 v = *(const float4*)&qkv_w[row * 64 + c4];
        s16x4 p = { f2s(v.x), f2s(v.y), f2s(v.z), f2s(v.w) };
        *(s16x4*)&s_w[lswz(row, c4)] = p;
    }
#pragma unroll
    for (int i = 0; i < 4; ++i) {               // proj_w: 4096 elems
        int g = i * 256 + t;
        int row = g >> 4, c4 = (g & 15) << 2;
        float4 v = *(const float4*)&proj_w[row * 64 + c4];
        s16x4 p = { f2s(v.x), f2s(v.y), f2s(v.z), f2s(v.w) };
        *(s16x4*)&s_wp[lswz(row, c4)] = p;
    }
    {
        // LN: 4 threads per token, 16 channels each
        int n = t >> 2, q = t & 3;
        int hp = (wh * 8 + (n >> 3) + 4) & 255;
        int wp = (wwi * 8 + (n & 7) + 4) & 255;
        const short* src = (const short*)xeb + (hp * 256 + wp) * 64 + q * 16;
        s16x8 u0 = *(const s16x8*)src;
        s16x8 u1 = *(const s16x8*)(src + 8);
        float v[16];
        float s = 0.f, sq = 0.f;
#pragma unroll
        for (int j = 0; j < 8; ++j) { v[j] = s2f(u0[j]); v[8 + j] = s2f(u1[j]); }
#pragma unroll
        for (int j = 0; j < 16; ++j) { s += v[j]; sq += v[j] * v[j]; }
        s  += __shfl_xor(s, 1);  s  += __shfl_xor(s, 2);
        sq += __shfl_xor(sq, 1); sq += __shfl_xor(sq, 2);
        float m = s * (1.f / 64.f);
        float rstd = rsqrtf(sq * (1.f / 64.f) - m * m + EPS_);
        s16x8 w0, w1;
#pragma unroll
        for (int j = 0; j < 8; ++j) {
            w0[j] = f2s((v[j] - m) * rstd * n1_g[q * 16 + j] + n1_b[q * 16 + j]);
            w1[j] = f2s((v[8 + j] - m) * rstd * n1_g[q * 16 + 8 + j] + n1_b[q * 16 + 8 + j]);
        }
        *(s16x8*)&s_x[lbase(n, q * 16)]     = w0;
        *(s16x8*)&s_x[lbase(n, q * 16 + 8)] = w1;
    }
    __syncthreads();

    // ---- stage 2: QKV GEMMs ----
    {
        const f32x4 cz = { 0.f, 0.f, 0.f, 0.f };
        int arow = w * 16 + lr;
        s16x8 a0 = ld8(&s_x[lbase(arow, lhi * 8)]);
        s16x8 a1 = ld8(&s_x[lbase(arow, 32 + lhi * 8)]);
#pragma unroll
        for (int nt = 0; nt < 8; ++nt) {        // Q: nt 0..3, K: nt 4..7
            int brow = nt * 16 + lr;            // output index o
            s16x8 b0 = ld8(&s_w[lbase(brow, lhi * 8)]);
            s16x8 b1 = ld8(&s_w[lbase(brow, 32 + lhi * 8)]);
            f32x4 c = cz;
            c = mfma16(a0, b0, c);
            c = mfma16(a1, b1, c);
            float bias = qkv_b[brow];
#pragma unroll
            for (int r = 0; r < 4; ++r) {
                int tok = w * 16 + lhi * 4 + r;
                float val = c[r] + bias;
                if (nt < 4) { val *= 0.25f; s_q[lswz(tok, nt * 16 + lr)] = f2s(val); }
                else        {               s_k[lswz(tok, (nt - 4) * 16 + lr)] = f2s(val); }
            }
        }
        // V^T: A = Wv rows, B = Xn-transposed-access
        s16x8 av0 = ld8(&s_w[lbase(128 + w * 16 + lr, lhi * 8)]);
        s16x8 av1 = ld8(&s_w[lbase(128 + w * 16 + lr, 32 + lhi * 8)]);
#pragma unroll
        for (int nt = 0; nt < 4; ++nt) {
            s16x8 b0 = ld8(&s_x[lbase(nt * 16 + lr, lhi * 8)]);
            s16x8 b1 = ld8(&s_x[lbase(nt * 16 + lr, 32 + lhi * 8)]);
            f32x4 c = cz;
            c = mfma16(av0, b0, c);
            c = mfma16(av1, b1, c);
#pragma unroll
            for (int r = 0; r < 4; ++r) {
                int d = w * 16 + lhi * 4 + r;
                s_vt[lswz(d, nt * 16 + lr)] = f2s(c[r] + qkv_b[128 + d]);
            }
        }
    }
    __syncthreads();

    // ---- stage 3: S = Q K^T (K=16, zero-padded to 32) + mask + softmax ----
    short* p_lds = (w == 0) ? s_x : &s_w[(w - 1) * 4096];   // per-head P buffer
    {
        const int h = w;
        const f32x4 cz = { 0.f, 0.f, 0.f, 0.f };
        const s16x8 z8 = { 0, 0, 0, 0, 0, 0, 0, 0 };
        s16x8 qa[4], kb[4];
#pragma unroll
        for (int mt = 0; mt < 4; ++mt)
            qa[mt] = ld8(&s_q[lbase(mt * 16 + lr, h * 16 + (lhi & 1) * 8)]);
#pragma unroll
        for (int nt = 0; nt < 4; ++nt) {
            s16x8 v = ld8(&s_k[lbase(nt * 16 + lr, h * 16 + (lhi & 1) * 8)]);
            kb[nt] = (lhi >= 2) ? z8 : v;       // zero k>=16 contribution
        }
        f32x4 S[4][4];
#pragma unroll
        for (int mt = 0; mt < 4; ++mt)
#pragma unroll
            for (int nt = 0; nt < 4; ++nt)
                S[mt][nt] = mfma16(qa[mt], kb[nt], cz);

        if (eh | ew) {
            int kcls[4];
#pragma unroll
            for (int nt = 0; nt < 4; ++nt) kcls[nt] = clsf(nt * 16 + lr, eh, ew);
#pragma unroll
            for (int mt = 0; mt < 4; ++mt)
#pragma unroll
                for (int r = 0; r < 4; ++r) {
                    int qc = clsf(mt * 16 + lhi * 4 + r, eh, ew);
#pragma unroll
                    for (int nt = 0; nt < 4; ++nt)
                        S[mt][nt][r] += (qc != kcls[nt]) ? -100.f : 0.f;
                }
        }
        // wave-parallel softmax per row (row lives in one 16-lane group)
#pragma unroll
        for (int mt = 0; mt < 4; ++mt)
#pragma unroll
            for (int r = 0; r < 4; ++r) {
                float mx = fmaxf(fmaxf(S[mt][0][r], S[mt][1][r]),
                                 fmaxf(S[mt][2][r], S[mt][3][r]));
                mx = fmaxf(mx, __shfl_xor(mx, 1));
                mx = fmaxf(mx, __shfl_xor(mx, 2));
                mx = fmaxf(mx, __shfl_xor(mx, 4));
                mx = fmaxf(mx, __shfl_xor(mx, 8));
                float e0 = __expf(S[mt][0][r] - mx);
                float e1 = __expf(S[mt][1][r] - mx);
                float e2 = __expf(S[mt][2][r] - mx);
                float e3 = __expf(S[mt][3][r] - mx);
                float sm = e0 + e1 + e2 + e3;
                sm += __shfl_xor(sm, 1);
                sm += __shfl_xor(sm, 2);
                sm += __shfl_xor(sm, 4);
                sm += __shfl_xor(sm, 8);
                float inv = 1.f / sm;
                int qtok = mt * 16 + lhi * 4 + r;
                p_lds[lswz(qtok, 0 * 16 + lr)] = f2s(e0 * inv);
                p_lds[lswz(qtok, 1 * 16 + lr)] = f2s(e1 * inv);
                p_lds[lswz(qtok, 2 * 16 + lr)] = f2s(e2 * inv);
                p_lds[lswz(qtok, 3 * 16 + lr)] = f2s(e3 * inv);
            }
    }
    __syncthreads();

    // ---- stage 4: O = P V  (per head; write O to s_o = s_q overlay) ----
    short* s_o = s_q;
    {
        const int h = w;
        const f32x4 cz = { 0.f, 0.f, 0.f, 0.f };
        f32x4 O[4] = { cz, cz, cz, cz };
#pragma unroll
        for (int ks = 0; ks < 2; ++ks) {
            s16x8 bv = ld8(&s_vt[lbase(h * 16 + lr, ks * 32 + lhi * 8)]);
#pragma unroll
            for (int mt = 0; mt < 4; ++mt) {
                s16x8 pa = ld8(&p_lds[lbase(mt * 16 + lr, ks * 32 + lhi * 8)]);
                O[mt] = mfma16(pa, bv, O[mt]);
            }
        }
#pragma unroll
        for (int mt = 0; mt < 4; ++mt)
#pragma unroll
            for (int r = 0; r < 4; ++r) {
                int tok = mt * 16 + lhi * 4 + r;
                s_o[lswz(tok, h * 16 + lr)] = f2s(O[mt][r]);
            }
    }
    __syncthreads();

    // ---- stage 5: proj + residual + store (window-reverse + roll fused) ----
    {
        const f32x4 cz = { 0.f, 0.f, 0.f, 0.f };
        int arow = w * 16 + lr;
        s16x8 a0 = ld8(&s_o[lbase(arow, lhi * 8)]);
        s16x8 a1 = ld8(&s_o[lbase(arow, 32 + lhi * 8)]);
        size_t rowbase[4];
#pragma unroll
        for (int r = 0; r < 4; ++r) {
            int tok = w * 16 + lhi * 4 + r;
            int hp = (wh * 8 + (tok >> 3) + 4) & 255;
            int wp = (wwi * 8 + (tok & 7) + 4) & 255;
            rowbase[r] = (size_t)(hp * 256 + wp) * 64;
        }
        const size_t bbase = (size_t)b * (H_ * W_ * ED_);
#pragma unroll
        for (int nt = 0; nt < 4; ++nt) {
            s16x8 b0 = ld8(&s_wp[lbase(nt * 16 + lr, lhi * 8)]);
            s16x8 b1 = ld8(&s_wp[lbase(nt * 16 + lr, 32 + lhi * 8)]);
            f32x4 c = cz;
            c = mfma16(a0, b0, c);
            c = mfma16(a1, b1, c);
            float bias = proj_b[nt * 16 + lr];
#pragma unroll
            for (int r = 0; r < 4; ++r) {
                size_t gi = rowbase[r] + nt * 16 + lr;
                float val = c[r] + bias + b2f(xeb[gi]);
                x_out[bbase + gi] = f2b(val);
            }
        }
    }
}

// ---------------------------------------------------------------------------
// Kernel 3: LN2 + fc1 + GELU + fc2 + residual, MFMA. 128 tokens/block, 8 waves.
// ---------------------------------------------------------------------------
__global__ __launch_bounds__(512) void k_mlp(
    const bf16* __restrict__ xo, const float* __restrict__ fc1_w,
    const float* __restrict__ fc1_b, const float* __restrict__ fc2_w,
    const float* __restrict__ fc2_b, const float* __restrict__ n2_g,
    const float* __restrict__ n2_b, bf16* __restrict__ xf)
{
    __shared__ short s_x[128 * 64];    // normalized tokens
    __shared__ short s_h[128 * 64];    // hidden chunk (wave-private row stripes)
    __shared__ short s_w1[64 * 64];
    __shared__ short s_w2[64 * 64];

    const int t    = threadIdx.x;
    const int w    = t >> 6;
    const int lane = t & 63;
    const int lr   = lane & 15;
    const int lhi  = lane >> 4;
    const size_t tok0 = (size_t)blockIdx.x * 128;
    const short* xos = (const short*)xo;

    // LN: 4 threads per token
    {
        int n = t >> 2, q = t & 3;
        const short* src = xos + (tok0 + n) * 64 + q * 16;
        s16x8 u0 = *(const s16x8*)src;
        s16x8 u1 = *(const s16x8*)(src + 8);
        float v[16];
        float s = 0.f, sq = 0.f;
#pragma unroll
        for (int j = 0; j < 8; ++j) { v[j] = s2f(u0[j]); v[8 + j] = s2f(u1[j]); }
#pragma unroll
        for (int j = 0; j < 16; ++j) { s += v[j]; sq += v[j] * v[j]; }
        s  += __shfl_xor(s, 1);  s  += __shfl_xor(s, 2);
        sq += __shfl_xor(sq, 1); sq += __shfl_xor(sq, 2);
        float m = s * (1.f / 64.f);
        float rstd = rsqrtf(sq * (1.f / 64.f) - m * m + EPS_);
        s16x8 w0, w1;
#pragma unroll
        for (int j = 0; j < 8; ++j) {
            w0[j] = f2s((v[j] - m) * rstd * n2_g[q * 16 + j] + n2_b[q * 16 + j]);
            w1[j] = f2s((v[8 + j] - m) * rstd * n2_g[q * 16 + 8 + j] + n2_b[q * 16 + 8 + j]);
        }
        *(s16x8*)&s_x[lbase(n, q * 16)]     = w0;
        *(s16x8*)&s_x[lbase(n, q * 16 + 8)] = w1;
    }

    const f32x4 cz = { 0.f, 0.f, 0.f, 0.f };
    f32x4 acc[4] = { cz, cz, cz, cz };
    const int arow = w * 16 + lr;

    for (int k = 0; k < 4; ++k) {
        __syncthreads();
        // stage fc1/fc2 weight chunks (fp32 -> bf16, swizzled)
#pragma unroll
        for (int i = 0; i < 2; ++i) {
            int g = i * 512 + t;
            int row = g >> 4, c4 = (g & 15) << 2;
            float4 a = *(const float4*)&fc1_w[(k * 64 + row) * 64 + c4];
            s16x4 pa = { f2s(a.x), f2s(a.y), f2s(a.z), f2s(a.w) };
            *(s16x4*)&s_w1[lswz(row, c4)] = pa;
            float4 bb = *(const float4*)&fc2_w[row * 256 + k * 64 + c4];
            s16x4 pb = { f2s(bb.x), f2s(bb.y), f2s(bb.z), f2s(bb.w) };
            *(s16x4*)&s_w2[lswz(row, c4)] = pb;
        }
        __syncthreads();

        // fc1 chunk + GELU -> s_h (own 16-row stripe)
        s16x8 a0 = ld8(&s_x[lbase(arow, lhi * 8)]);
        s16x8 a1 = ld8(&s_x[lbase(arow, 32 + lhi * 8)]);
#pragma unroll
        for (int nt = 0; nt < 4; ++nt) {
            s16x8 b0 = ld8(&s_w1[lbase(nt * 16 + lr, lhi * 8)]);
            s16x8 b1 = ld8(&s_w1[lbase(nt * 16 + lr, 32 + lhi * 8)]);
            f32x4 c = cz;
            c = mfma16(a0, b0, c);
            c = mfma16(a1, b1, c);
            float bias = fc1_b[k * 64 + nt * 16 + lr];
#pragma unroll
            for (int r = 0; r < 4; ++r) {
                float hv = c[r] + bias;
                hv = 0.5f * hv * (1.f + erff(hv * 0.70710678118f));
                s_h[lswz(w * 16 + lhi * 4 + r, nt * 16 + lr)] = f2s(hv);
            }
        }
        // fc2 partial (reads own stripe; same-wave LDS ordering)
        s16x8 h0 = ld8(&s_h[lbase(arow, lhi * 8)]);
        s16x8 h1 = ld8(&s_h[lbase(arow, 32 + lhi * 8)]);
#pragma unroll
        for (int nt = 0; nt < 4; ++nt) {
            s16x8 b0 = ld8(&s_w2[lbase(nt * 16 + lr, lhi * 8)]);
            s16x8 b1 = ld8(&s_w2[lbase(nt * 16 + lr, 32 + lhi * 8)]);
            acc[nt] = mfma16(h0, b0, acc[nt]);
            acc[nt] = mfma16(h1, b1, acc[nt]);
        }
    }

    // epilogue: bias + residual + store
#pragma unroll
    for (int nt = 0; nt < 4; ++nt) {
        float bias = fc2_b[nt * 16 + lr];
#pragma unroll
        for (int r = 0; r < 4; ++r) {
            int tok = w * 16 + lhi * 4 + r;
            size_t gi = (tok0 + tok) * 64 + nt * 16 + lr;
            float v = acc[nt][r] + bias + s2f(xos[gi]);
            ((short*)xf)[gi] = f2s(v);
        }
    }
}

// ---------------------------------------------------------------------------
// Kernel 4: conv up 3x3, ED=64 -> CIN=3, as MFMA GEMM (M=pixels, N=3 pad 16,
// K=9 taps x 64 ci). Block = 64-pixel row segment, 4 waves x 16 pixels.
// xf halo tile (3x66x64) + weight B-fragments staged in LDS.
// ---------------------------------------------------------------------------
__global__ __launch_bounds__(256) void k_conv_up(
    const float* __restrict__ x, const bf16* __restrict__ xf,
    const float* __restrict__ wu, const float* __restrict__ bu,
    float* __restrict__ out)
{
    __shared__ short s_t[198 * 64];    // xf tile [kh*66 + wx_local][ci], swizzled
    __shared__ short s_bf[1152 * 8];   // B-fragments [(tap*2+half)*64 + lane][8]
    __shared__ float s_wu[1728];       // wu fp32 staging

    const int t    = threadIdx.x;
    const int pix0 = blockIdx.x * 64;
    const int b    = pix0 >> 16;
    const int h    = (pix0 >> 8) & 255;
    const int w0   = pix0 & 255;

    const short* xfs = (const short*)xf;

    // stage xf halo tile (rows h-1..h+1, cols w0-1..w0+64), zero-pad OOB
    for (int e = t; e < 1584; e += 256) {
        int rc = e >> 3, j8 = e & 7;
        int hy_l = (unsigned)rc / 66u;
        int wx_l = rc - hy_l * 66;
        int hy = h + hy_l - 1;
        int wx = w0 + wx_l - 1;
        s16x8 v = { 0, 0, 0, 0, 0, 0, 0, 0 };
        if (((unsigned)hy < 256u) & ((unsigned)wx < 256u))
            v = *(const s16x8*)&xfs[((size_t)((b * 256 + hy) * 256 + wx)) * 64 + j8 * 8];
        *(s16x8*)&s_t[lbase(rc, j8 * 8)] = v;
    }
    // stage wu fp32 (coalesced; 1728 elems)
    for (int e = t; e < 1728; e += 256) s_wu[e] = wu[e];
    __syncthreads();

    // build B fragments: B[col=co][k=ci] per (tap, k-half); co>=3 zero
    for (int fid = t; fid < 1152; fid += 256) {
        int tap  = fid >> 7;
        int half = (fid >> 6) & 1;
        int ln   = fid & 63;
        int co   = ln & 15;
        s16x8 v = { 0, 0, 0, 0, 0, 0, 0, 0 };
        if (co < 3) {
            int ci0 = half * 32 + (ln >> 4) * 8;
#pragma unroll
            for (int j = 0; j < 8; ++j)
                v[j] = f2s(s_wu[(co * 64 + ci0 + j) * 9 + tap]);
        }
        *(s16x8*)&s_bf[fid * 8] = v;
    }
    __syncthreads();

    const int wv   = t >> 6;
    const int lane = t & 63;
    const int lr   = lane & 15;
    const int lhi  = lane >> 4;

    f32x4 acc = { 0.f, 0.f, 0.f, 0.f };
#pragma unroll
    for (int kh = 0; kh < 3; ++kh)
#pragma unroll
        for (int kw = 0; kw < 3; ++kw) {
            const int tap = kh * 3 + kw;
            const int R   = kh * 66 + wv * 16 + lr + kw;   // A row: pixel (rolled by tap)
#pragma unroll
            for (int half = 0; half < 2; ++half) {
                s16x8 a   = ld8(&s_t[lbase(R, half * 32 + lhi * 8)]);
                s16x8 bfr = ld8(&s_bf[((tap * 2 + half) * 64 + lane) * 8]);
                acc = mfma16(a, bfr, acc);
            }
        }

    // D: col = lr = co (only co<3), row = lhi*4 + r = pixel -> float4 store
    if (lr < 3) {
        const int co = lr;
        const int wp = wv * 16 + lhi * 4;
        size_t o0 = (size_t)b * 3 * 65536 + (size_t)co * 65536 + (size_t)h * 256 + w0 + wp;
        float4 xv = *(const float4*)&x[o0];
        float bias = bu[co];
        float4 ov;
        ov.x = acc[0] + bias + xv.x;
        ov.y = acc[1] + bias + xv.y;
        ov.z = acc[2] + bias + xv.z;
        ov.w = acc[3] + bias + xv.w;
        *(float4*)&out[o0] = ov;
    }
}

// ---------------------------------------------------------------------------
extern "C" void kernel_launch(void* const* d_in, const int* in_sizes, int n_in,
                              void* d_out, int out_size, void* d_ws, size_t ws_size,
                              hipStream_t stream)
{
    const float* x     = (const float*)d_in[0];
    const float* cew   = (const float*)d_in[1];
    const float* ceb   = (const float*)d_in[2];
    const float* n1g   = (const float*)d_in[3];
    const float* n1b   = (const float*)d_in[4];
    const float* qkvw  = (const float*)d_in[5];
    const float* qkvb  = (const float*)d_in[6];
    const float* projw = (const float*)d_in[7];
    const float* projb = (const float*)d_in[8];
    const float* n2g   = (const float*)d_in[9];
    const float* n2b   = (const float*)d_in[10];
    const float* fc1w  = (const float*)d_in[11];
    const float* fc1b  = (const float*)d_in[12];
    const float* fc2w  = (const float*)d_in[13];
    const float* fc2b  = (const float*)d_in[14];
    const float* cuw   = (const float*)d_in[15];
    const float* cub   = (const float*)d_in[16];
    float* out = (float*)d_out;

    const size_t planeElems = (size_t)B_ * H_ * W_ * ED_;   // 33.5M
    bf16* xe = (bf16*)d_ws;                                  // also x_final later
    bf16* xo = (bf16*)((char*)d_ws + planeElems * sizeof(bf16));

    hipLaunchKernelGGL(k_conv_embed, dim3(2048), dim3(256), 0, stream, x, cew, ceb, xe);
    hipLaunchKernelGGL(k_attn,       dim3(8192), dim3(256), 0, stream,
                       xe, qkvw, qkvb, projw, projb, n1g, n1b, xo);
    hipLaunchKernelGGL(k_mlp,        dim3(4096), dim3(512), 0, stream,
                       xo, fc1w, fc1b, fc2w, fc2b, n2g, n2b, xe);
    hipLaunchKernelGGL(k_conv_up,    dim3(8192), dim3(256), 0, stream, x, xe, cuw, cub, out);
}